// Round 14
// baseline (46.335 us; speedup 1.0000x reference)
//
#include <hip/hip_runtime.h>

namespace {
constexpr int C  = 12;
constexpr int D  = 8;
constexpr int HI = 16;
constexpr int WI = 16;
constexpr int IMG_H = 1080;
constexpr int IMG_W = 1920;
constexpr int PIX = IMG_H * IMG_W;
constexpr int DSTRIDE = WI * C + 4;       // 196 dwords: de-alias z-slabs, keep 16B align
constexpr int ROWTAB  = D * DSTRIDE;      // 1568 floats per row table
constexpr int PX_PER_BLOCK = 1024;        // 256 threads x 4 px
constexpr int NBLOCKS = PIX / PX_PER_BLOCK; // 2025 exactly

typedef float f32x4 __attribute__((ext_vector_type(4)));

__global__ __launch_bounds__(256) void slice(const float* __restrict__ grid5,
                                             const float* __restrict__ guide,
                                             float* __restrict__ out) {
    __shared__ float gy[2 * ROWTAB];      // up to 2 row tables, 12.5 KB

    const int tid   = threadIdx.x;
    const int pblk  = blockIdx.x * PX_PER_BLOCK;
    const int r0    = pblk / IMG_W;
    const int rlast = (pblk + PX_PER_BLOCK - 1) / IMG_W;
    const int nrows = rlast - r0 + 1;     // 1 or 2

    // --- phase 1: fold y-interpolation into LDS per row table ---
    for (int rr = 0; rr < nrows; ++rr) {
        const int   row  = r0 + rr;
        const float hgv  = (float)row * (2.0f / (IMG_H - 1)) - 1.0f;
        const float iy   = ((hgv + 1.0f) * (float)HI - 1.0f) * 0.5f;
        const float iy0f = floorf(iy);
        const float fy   = iy - iy0f;
        const int   iy0  = (int)iy0f, iy1 = iy0 + 1;
        const float wy0  = (iy0 >= 0 && iy0 < HI) ? (1.0f - fy) : 0.0f;
        const float wy1  = (iy1 >= 0 && iy1 < HI) ? fy : 0.0f;
        const int   y0c  = min(max(iy0, 0), HI - 1);
        const int   y1c  = min(max(iy1, 0), HI - 1);

        // i = (c*D + d)*WI + x  -> global reads have x lane-fastest (coalesced)
        for (int i = tid; i < C * D * WI; i += 256) {
            const int x  = i & (WI - 1);
            const int cd = i >> 4;        // c*D + d
            const int d  = cd & (D - 1);
            const int c  = cd >> 3;
            const int gbase = ((c * D + d) * HI) * WI + x;
            const float v = wy0 * grid5[gbase + y0c * WI]
                          + wy1 * grid5[gbase + y1c * WI];
            gy[rr * ROWTAB + d * DSTRIDE + x * C + c] = v;
        }
    }
    __syncthreads();

    // --- phase 2: 4 contiguous px per thread ---
    const int p0   = pblk + tid * 4;
    const int row  = p0 / IMG_W;          // uniform per thread (4 | 1920)
    const int col0 = p0 - row * IMG_W;
    const float* __restrict__ gyb = gy + (row - r0) * ROWTAB;

    const float4 g4 = *reinterpret_cast<const float4*>(guide + p0);
    const float gx[4] = {g4.x, g4.y, g4.z, g4.w};

    float acc[4][12];

    #pragma unroll
    for (int j = 0; j < 4; ++j) {
        // z (column) interpolation
        const int   w    = col0 + j;
        const float wgv  = (float)w * (2.0f / (IMG_W - 1)) - 1.0f;
        const float iz   = ((wgv + 1.0f) * (float)D - 1.0f) * 0.5f;
        const float iz0f = floorf(iz);
        const float fz   = iz - iz0f;
        const int   iz0  = (int)iz0f, iz1 = iz0 + 1;
        const float wz0  = (iz0 >= 0 && iz0 < D) ? (1.0f - fz) : 0.0f;
        const float wz1  = (iz1 >= 0 && iz1 < D) ? fz : 0.0f;
        const int   zo0  = min(max(iz0, 0), D - 1) * DSTRIDE;
        const int   zo1  = min(max(iz1, 0), D - 1) * DSTRIDE;

        // x from guidemap value
        const float xv   = gx[j];
        const float ix   = ((xv + 1.0f) * (float)WI - 1.0f) * 0.5f;
        const float ix0f = floorf(ix);
        const float fx   = ix - ix0f;
        const int   ix0  = (int)ix0f, ix1 = ix0 + 1;
        const float wx0  = (ix0 >= 0 && ix0 < WI) ? (1.0f - fx) : 0.0f;
        const float wx1  = (ix0 + 1 >= 0 && ix0 + 1 < WI) ? fx : 0.0f;
        const int   xo0  = min(max(ix0, 0), WI - 1) * C;
        const int   xo1  = min(max(ix1, 0), WI - 1) * C;

        const float wt[4]   = { wz0 * wx0, wz0 * wx1, wz1 * wx0, wz1 * wx1 };
        const int   idx4[4] = { zo0 + xo0, zo0 + xo1, zo1 + xo0, zo1 + xo1 };

        float a[12];
        #pragma unroll
        for (int c = 0; c < 12; ++c) a[c] = 0.0f;

        #pragma unroll
        for (int k = 0; k < 4; ++k) {
            const float wk = wt[k];
            const float4* p = reinterpret_cast<const float4*>(&gyb[idx4[k]]);
            const float4 v0 = p[0];
            const float4 v1 = p[1];
            const float4 v2 = p[2];
            a[0]  = fmaf(wk, v0.x, a[0]);   a[1]  = fmaf(wk, v0.y, a[1]);
            a[2]  = fmaf(wk, v0.z, a[2]);   a[3]  = fmaf(wk, v0.w, a[3]);
            a[4]  = fmaf(wk, v1.x, a[4]);   a[5]  = fmaf(wk, v1.y, a[5]);
            a[6]  = fmaf(wk, v1.z, a[6]);   a[7]  = fmaf(wk, v1.w, a[7]);
            a[8]  = fmaf(wk, v2.x, a[8]);   a[9]  = fmaf(wk, v2.y, a[9]);
            a[10] = fmaf(wk, v2.z, a[10]);  a[11] = fmaf(wk, v2.w, a[11]);
        }
        #pragma unroll
        for (int c = 0; c < 12; ++c) acc[j][c] = a[c];
    }

    #pragma unroll
    for (int c = 0; c < 12; ++c) {
        f32x4 o = { acc[0][c], acc[1][c], acc[2][c], acc[3][c] };
        __builtin_nontemporal_store(o, reinterpret_cast<f32x4*>(out + c * PIX + p0));
    }
}
} // namespace

extern "C" void kernel_launch(void* const* d_in, const int* in_sizes, int n_in,
                              void* d_out, int out_size, void* d_ws, size_t ws_size,
                              hipStream_t stream) {
    const float* grid5 = (const float*)d_in[0];   // [1,12,8,16,16] fp32
    const float* guide = (const float*)d_in[1];   // [1,1,1080,1920] fp32
    float* out = (float*)d_out;                   // [1,12,1080,1920] fp32

    // R13 DIAGNOSTIC: launch twice (idempotent — identical inputs/outputs).
    // Marginal cost of launch #2 = true kernel execution time, separating
    // fixed per-replay overhead from real HBM work. Revert next round.
    hipLaunchKernelGGL(slice, dim3(NBLOCKS), dim3(256), 0, stream,
                       grid5, guide, out);
    hipLaunchKernelGGL(slice, dim3(NBLOCKS), dim3(256), 0, stream,
                       grid5, guide, out);
}

// Round 15
// 32.304 us; speedup vs baseline: 1.4343x; 1.4343x over previous
//
#include <hip/hip_runtime.h>

namespace {
constexpr int C  = 12;
constexpr int D  = 8;
constexpr int HI = 16;
constexpr int WI = 16;
constexpr int IMG_H = 1080;
constexpr int IMG_W = 1920;
constexpr int PIX = IMG_H * IMG_W;
constexpr int DSTRIDE = WI * C + 4;       // 196 dwords: de-alias z-slabs, keep 16B align
constexpr int ROWTAB  = D * DSTRIDE;      // 1568 floats per row table
constexpr int PX_PER_BLOCK = 1024;        // 256 threads x 4 px
constexpr int NBLOCKS = PIX / PX_PER_BLOCK; // 2025 exactly

typedef float f32x4 __attribute__((ext_vector_type(4)));

__global__ __launch_bounds__(256) void slice(const float* __restrict__ grid5,
                                             const float* __restrict__ guide,
                                             float* __restrict__ out) {
    __shared__ float gy[2 * ROWTAB];      // up to 2 row tables, 12.5 KB

    const int tid   = threadIdx.x;
    const int pblk  = blockIdx.x * PX_PER_BLOCK;
    const int r0    = pblk / IMG_W;
    const int rlast = (pblk + PX_PER_BLOCK - 1) / IMG_W;
    const int nrows = rlast - r0 + 1;     // 1 or 2

    // --- phase 1: fold y-interpolation into LDS per row table ---
    for (int rr = 0; rr < nrows; ++rr) {
        const int   row  = r0 + rr;
        const float hgv  = (float)row * (2.0f / (IMG_H - 1)) - 1.0f;
        const float iy   = ((hgv + 1.0f) * (float)HI - 1.0f) * 0.5f;
        const float iy0f = floorf(iy);
        const float fy   = iy - iy0f;
        const int   iy0  = (int)iy0f, iy1 = iy0 + 1;
        const float wy0  = (iy0 >= 0 && iy0 < HI) ? (1.0f - fy) : 0.0f;
        const float wy1  = (iy1 >= 0 && iy1 < HI) ? fy : 0.0f;
        const int   y0c  = min(max(iy0, 0), HI - 1);
        const int   y1c  = min(max(iy1, 0), HI - 1);

        // i = (c*D + d)*WI + x  -> global reads have x lane-fastest (coalesced)
        for (int i = tid; i < C * D * WI; i += 256) {
            const int x  = i & (WI - 1);
            const int cd = i >> 4;        // c*D + d
            const int d  = cd & (D - 1);
            const int c  = cd >> 3;
            const int gbase = ((c * D + d) * HI) * WI + x;
            const float v = wy0 * grid5[gbase + y0c * WI]
                          + wy1 * grid5[gbase + y1c * WI];
            gy[rr * ROWTAB + d * DSTRIDE + x * C + c] = v;
        }
    }
    __syncthreads();

    // --- phase 2: 4 contiguous px per thread ---
    const int p0   = pblk + tid * 4;
    const int row  = p0 / IMG_W;          // uniform per thread (4 | 1920)
    const int col0 = p0 - row * IMG_W;
    const float* __restrict__ gyb = gy + (row - r0) * ROWTAB;

    // nontemporal streaming read: guide is read-once, keep it out of L2
    const f32x4 g4 = __builtin_nontemporal_load(
        reinterpret_cast<const f32x4*>(guide + p0));
    const float gx[4] = {g4.x, g4.y, g4.z, g4.w};

    float acc[4][12];

    #pragma unroll
    for (int j = 0; j < 4; ++j) {
        // z (column) interpolation
        const int   w    = col0 + j;
        const float wgv  = (float)w * (2.0f / (IMG_W - 1)) - 1.0f;
        const float iz   = ((wgv + 1.0f) * (float)D - 1.0f) * 0.5f;
        const float iz0f = floorf(iz);
        const float fz   = iz - iz0f;
        const int   iz0  = (int)iz0f, iz1 = iz0 + 1;
        const float wz0  = (iz0 >= 0 && iz0 < D) ? (1.0f - fz) : 0.0f;
        const float wz1  = (iz1 >= 0 && iz1 < D) ? fz : 0.0f;
        const int   zo0  = min(max(iz0, 0), D - 1) * DSTRIDE;
        const int   zo1  = min(max(iz1, 0), D - 1) * DSTRIDE;

        // x from guidemap value
        const float xv   = gx[j];
        const float ix   = ((xv + 1.0f) * (float)WI - 1.0f) * 0.5f;
        const float ix0f = floorf(ix);
        const float fx   = ix - ix0f;
        const int   ix0  = (int)ix0f, ix1 = ix0 + 1;
        const float wx0  = (ix0 >= 0 && ix0 < WI) ? (1.0f - fx) : 0.0f;
        const float wx1  = (ix1 >= 0 && ix1 < WI) ? fx : 0.0f;
        const int   xo0  = min(max(ix0, 0), WI - 1) * C;
        const int   xo1  = min(max(ix1, 0), WI - 1) * C;

        const float wt[4]   = { wz0 * wx0, wz0 * wx1, wz1 * wx0, wz1 * wx1 };
        const int   idx4[4] = { zo0 + xo0, zo0 + xo1, zo1 + xo0, zo1 + xo1 };

        float a[12];
        #pragma unroll
        for (int c = 0; c < 12; ++c) a[c] = 0.0f;

        #pragma unroll
        for (int k = 0; k < 4; ++k) {
            const float wk = wt[k];
            const float4* p = reinterpret_cast<const float4*>(&gyb[idx4[k]]);
            const float4 v0 = p[0];
            const float4 v1 = p[1];
            const float4 v2 = p[2];
            a[0]  = fmaf(wk, v0.x, a[0]);   a[1]  = fmaf(wk, v0.y, a[1]);
            a[2]  = fmaf(wk, v0.z, a[2]);   a[3]  = fmaf(wk, v0.w, a[3]);
            a[4]  = fmaf(wk, v1.x, a[4]);   a[5]  = fmaf(wk, v1.y, a[5]);
            a[6]  = fmaf(wk, v1.z, a[6]);   a[7]  = fmaf(wk, v1.w, a[7]);
            a[8]  = fmaf(wk, v2.x, a[8]);   a[9]  = fmaf(wk, v2.y, a[9]);
            a[10] = fmaf(wk, v2.z, a[10]);  a[11] = fmaf(wk, v2.w, a[11]);
        }
        #pragma unroll
        for (int c = 0; c < 12; ++c) acc[j][c] = a[c];
    }

    #pragma unroll
    for (int c = 0; c < 12; ++c) {
        f32x4 o = { acc[0][c], acc[1][c], acc[2][c], acc[3][c] };
        __builtin_nontemporal_store(o, reinterpret_cast<f32x4*>(out + c * PIX + p0));
    }
}
} // namespace

extern "C" void kernel_launch(void* const* d_in, const int* in_sizes, int n_in,
                              void* d_out, int out_size, void* d_ws, size_t ws_size,
                              hipStream_t stream) {
    const float* grid5 = (const float*)d_in[0];   // [1,12,8,16,16] fp32
    const float* guide = (const float*)d_in[1];   // [1,1,1080,1920] fp32
    float* out = (float*)d_out;                   // [1,12,1080,1920] fp32

    hipLaunchKernelGGL(slice, dim3(NBLOCKS), dim3(256), 0, stream,
                       grid5, guide, out);
}

// Round 16
// 25.413 us; speedup vs baseline: 1.8233x; 1.2712x over previous
//
#include <hip/hip_runtime.h>

namespace {
constexpr int C  = 12;
constexpr int D  = 8;
constexpr int HI = 16;
constexpr int WI = 16;
constexpr int IMG_H = 1080;
constexpr int IMG_W = 1920;
constexpr int PIX = IMG_H * IMG_W;
constexpr int DSTRIDE = WI * C + 4;       // 196 dwords: de-alias z-slabs, keep 16B align
constexpr int ROWTAB  = D * DSTRIDE;      // 1568 floats per row table
constexpr int PX_PER_BLOCK = 1024;        // 256 threads x 4 px
constexpr int NBLOCKS = PIX / PX_PER_BLOCK; // 2025 exactly

typedef float f32x4 __attribute__((ext_vector_type(4)));

__global__ __launch_bounds__(256) void slice(const float* __restrict__ grid5,
                                             const float* __restrict__ guide,
                                             float* __restrict__ out) {
    __shared__ float gy[2 * ROWTAB];      // up to 2 row tables, 12.5 KB

    const int tid   = threadIdx.x;
    const int pblk  = blockIdx.x * PX_PER_BLOCK;
    const int r0    = pblk / IMG_W;
    const int rlast = (pblk + PX_PER_BLOCK - 1) / IMG_W;
    const int nrows = rlast - r0 + 1;     // 1 or 2

    // --- phase 1: fold y-interpolation into LDS per row table ---
    for (int rr = 0; rr < nrows; ++rr) {
        const int   row  = r0 + rr;
        const float hgv  = (float)row * (2.0f / (IMG_H - 1)) - 1.0f;
        const float iy   = ((hgv + 1.0f) * (float)HI - 1.0f) * 0.5f;
        const float iy0f = floorf(iy);
        const float fy   = iy - iy0f;
        const int   iy0  = (int)iy0f, iy1 = iy0 + 1;
        const float wy0  = (iy0 >= 0 && iy0 < HI) ? (1.0f - fy) : 0.0f;
        const float wy1  = (iy1 >= 0 && iy1 < HI) ? fy : 0.0f;
        const int   y0c  = min(max(iy0, 0), HI - 1);
        const int   y1c  = min(max(iy1, 0), HI - 1);

        // i = (c*D + d)*WI + x  -> global reads have x lane-fastest (coalesced)
        for (int i = tid; i < C * D * WI; i += 256) {
            const int x  = i & (WI - 1);
            const int cd = i >> 4;        // c*D + d
            const int d  = cd & (D - 1);
            const int c  = cd >> 3;
            const int gbase = ((c * D + d) * HI) * WI + x;
            const float v = wy0 * grid5[gbase + y0c * WI]
                          + wy1 * grid5[gbase + y1c * WI];
            gy[rr * ROWTAB + d * DSTRIDE + x * C + c] = v;
        }
    }
    __syncthreads();

    // --- phase 2: 4 contiguous px per thread ---
    const int p0   = pblk + tid * 4;
    const int row  = p0 / IMG_W;          // uniform per thread (4 | 1920)
    const int col0 = p0 - row * IMG_W;
    const float* __restrict__ gyb = gy + (row - r0) * ROWTAB;

    const float4 g4 = *reinterpret_cast<const float4*>(guide + p0);
    const float gx[4] = {g4.x, g4.y, g4.z, g4.w};

    float acc[4][12];

    #pragma unroll
    for (int j = 0; j < 4; ++j) {
        // z (column) interpolation
        const int   w    = col0 + j;
        const float wgv  = (float)w * (2.0f / (IMG_W - 1)) - 1.0f;
        const float iz   = ((wgv + 1.0f) * (float)D - 1.0f) * 0.5f;
        const float iz0f = floorf(iz);
        const float fz   = iz - iz0f;
        const int   iz0  = (int)iz0f, iz1 = iz0 + 1;
        const float wz0  = (iz0 >= 0 && iz0 < D) ? (1.0f - fz) : 0.0f;
        const float wz1  = (iz1 >= 0 && iz1 < D) ? fz : 0.0f;
        const int   zo0  = min(max(iz0, 0), D - 1) * DSTRIDE;
        const int   zo1  = min(max(iz1, 0), D - 1) * DSTRIDE;

        // x from guidemap value
        const float xv   = gx[j];
        const float ix   = ((xv + 1.0f) * (float)WI - 1.0f) * 0.5f;
        const float ix0f = floorf(ix);
        const float fx   = ix - ix0f;
        const int   ix0  = (int)ix0f, ix1 = ix0 + 1;
        const float wx0  = (ix0 >= 0 && ix0 < WI) ? (1.0f - fx) : 0.0f;
        const float wx1  = (ix1 >= 0 && ix1 < WI) ? fx : 0.0f;
        const int   xo0  = min(max(ix0, 0), WI - 1) * C;
        const int   xo1  = min(max(ix1, 0), WI - 1) * C;

        const float wt[4]   = { wz0 * wx0, wz0 * wx1, wz1 * wx0, wz1 * wx1 };
        const int   idx4[4] = { zo0 + xo0, zo0 + xo1, zo1 + xo0, zo1 + xo1 };

        float a[12];
        #pragma unroll
        for (int c = 0; c < 12; ++c) a[c] = 0.0f;

        #pragma unroll
        for (int k = 0; k < 4; ++k) {
            const float wk = wt[k];
            const float4* p = reinterpret_cast<const float4*>(&gyb[idx4[k]]);
            const float4 v0 = p[0];
            const float4 v1 = p[1];
            const float4 v2 = p[2];
            a[0]  = fmaf(wk, v0.x, a[0]);   a[1]  = fmaf(wk, v0.y, a[1]);
            a[2]  = fmaf(wk, v0.z, a[2]);   a[3]  = fmaf(wk, v0.w, a[3]);
            a[4]  = fmaf(wk, v1.x, a[4]);   a[5]  = fmaf(wk, v1.y, a[5]);
            a[6]  = fmaf(wk, v1.z, a[6]);   a[7]  = fmaf(wk, v1.w, a[7]);
            a[8]  = fmaf(wk, v2.x, a[8]);   a[9]  = fmaf(wk, v2.y, a[9]);
            a[10] = fmaf(wk, v2.z, a[10]);  a[11] = fmaf(wk, v2.w, a[11]);
        }
        #pragma unroll
        for (int c = 0; c < 12; ++c) acc[j][c] = a[c];
    }

    #pragma unroll
    for (int c = 0; c < 12; ++c) {
        f32x4 o = { acc[0][c], acc[1][c], acc[2][c], acc[3][c] };
        __builtin_nontemporal_store(o, reinterpret_cast<f32x4*>(out + c * PIX + p0));
    }
}
} // namespace

extern "C" void kernel_launch(void* const* d_in, const int* in_sizes, int n_in,
                              void* d_out, int out_size, void* d_ws, size_t ws_size,
                              hipStream_t stream) {
    const float* grid5 = (const float*)d_in[0];   // [1,12,8,16,16] fp32
    const float* guide = (const float*)d_in[1];   // [1,1,1080,1920] fp32
    float* out = (float*)d_out;                   // [1,12,1080,1920] fp32

    hipLaunchKernelGGL(slice, dim3(NBLOCKS), dim3(256), 0, stream,
                       grid5, guide, out);
}